// Round 14
// baseline (1527.530 us; speedup 1.0000x reference)
//
#include <hip/hip_runtime.h>
#include <hip/hip_bf16.h>

typedef __attribute__((ext_vector_type(8))) short bf16x8;
typedef __attribute__((ext_vector_type(4))) short s16x4;
typedef __attribute__((ext_vector_type(4))) float f32x4;

// LDS: 32 KB = 4 wave-strips x 8192 B. During proj1: strip = X dbuf 2x[16 rows][64 f32],
// row 256B, 16B-slot s holds global slot s^row (XOR swizzle via source).
// After proj1 (per-wave alias, shorts rel. strip): scratch Q/PT/Y @0 (1280) ;
// K[16][72] @1280 ; VT-block[64][16] @2432 ; end 3456 <= 4096.
#define LDS_SHORTS 16384

__device__ __forceinline__ short f2b(float f) {
    __hip_bfloat16 h = __float2bfloat16(f);
    return __builtin_bit_cast(short, h);
}

// Fragment-major weight packing (R10 layout): W1 block (ot*24 + k32), W2 block (u*2+half),
// each 512 shorts lane-major; kernel loads base + lane*16B (coalesced).
__global__ void cvt_weights(const float* __restrict__ W1, const float* __restrict__ W2,
                            short* __restrict__ w1b, short* __restrict__ w2b) {
    int i = blockIdx.x * 256 + threadIdx.x;
    if (i < 192 * 768) {
        int B = i >> 9, r = i & 511;
        int lane = r >> 3, j = r & 7;
        int g = lane >> 4, c = lane & 15;
        int ot = B / 24, k32 = B - ot * 24;
        w1b[i] = f2b(W1[(16 * ot + c) * 768 + k32 * 32 + 8 * g + j]);
    }
    if (i < 768 * 64) {
        int B = i >> 9, r = i & 511;
        int lane = r >> 3, j = r & 7;
        int g = lane >> 4, c = lane & 15;
        int u = B >> 1, half = B & 1;
        w2b[i] = f2b(W2[(16 * u + c) * 64 + half * 32 + 8 * g + j]);
    }
}

__device__ __forceinline__ void gload_lds16(const float* g, unsigned char* l) {
    __builtin_amdgcn_global_load_lds(
        (const __attribute__((address_space(1))) void*)g,
        (__attribute__((address_space(3))) void*)l, 16, 0, 0);
}

#define VMW(n)   asm volatile("s_waitcnt vmcnt(" #n ")" ::: "memory")
#define LGKM0()  asm volatile("s_waitcnt lgkmcnt(0)" ::: "memory")
#define SCHEDB() __builtin_amdgcn_sched_barrier(0)

// Wave-private proj1: wave w owns rows 16w..16w+15 x all 192 o-cols. Zero barriers.
// Rolling W reload keeps ~28 loads in flight per wave (R7 lesson: never load-then-use).
__global__ __launch_bounds__(256, 3)
void tiny_att(const float* __restrict__ x, const float* __restrict__ b1v,
              const float* __restrict__ b2v, const short* __restrict__ W1b,
              const short* __restrict__ W2b, float* __restrict__ out) {
    __shared__ __align__(16) short S[LDS_SHORTS];
    unsigned char* L = (unsigned char*)S;
    const int tid  = threadIdx.x;
    const int wid  = tid >> 6;
    const int lane = tid & 63;
    const int g    = lane >> 4;
    const int c    = lane & 15;
    const int win  = blockIdx.x;
    const float* xg = x + (size_t)win * 49152;
    const int qb = wid * 4096;            // strip base (shorts)
    const f32x4 zero4 = {0.f, 0.f, 0.f, 0.f};

    // ---------------- proj1 ----------------
    f32x4 acc[12];
    #pragma unroll
    for (int i = 0; i < 12; ++i) acc[i] = zero4;
    bf16x8 W[2][12];

    // stage chunk kc (wave's 16 rows x 64 f32) -> strip buf b; source XOR-swizzled
    auto STAGE = [&](int kc, int b) {
        #pragma unroll
        for (int j = 0; j < 4; ++j) {
            int rr = j * 4 + (lane >> 4);
            const float* gsrc = xg + (16 * wid + rr) * 768 + kc * 64 + (((lane & 15) ^ rr) << 2);
            gload_lds16(gsrc, L + wid * 8192 + b * 4096 + j * 1024);
        }
    };

    STAGE(0, 0);
    STAGE(1, 1);
    #pragma unroll
    for (int ks = 0; ks < 2; ++ks)
        #pragma unroll
        for (int oi = 0; oi < 12; ++oi)
            W[ks][oi] = *(const bf16x8*)(W1b + ((oi * 24 + ks) << 9) + lane * 8);

    #pragma unroll 1
    for (int kc = 0; kc < 12; ++kc) {
        if (kc < 11) { VMW(28); } else { VMW(24); }   // stage(kc) landed; 28 newer keep flying
        SCHEDB();
        const int b = kc & 1;
        const unsigned char* Lb = L + wid * 8192 + b * 4096 + c * 256;
        bf16x8 a[2];
        #pragma unroll
        for (int ks = 0; ks < 2; ++ks) {
            int gs = 8 * ks + 2 * g;
            f32x4 lo = *(const f32x4*)(Lb + ((gs ^ c) << 4));
            f32x4 hi = *(const f32x4*)(Lb + (((gs + 1) ^ c) << 4));
            a[ks][0] = f2b(lo[0]); a[ks][1] = f2b(lo[1]);
            a[ks][2] = f2b(lo[2]); a[ks][3] = f2b(lo[3]);
            a[ks][4] = f2b(hi[0]); a[ks][5] = f2b(hi[1]);
            a[ks][6] = f2b(hi[2]); a[ks][7] = f2b(hi[3]);
        }
        LGKM0();            // strip reads retired before async overwrite
        SCHEDB();
        if (kc + 2 < 12) STAGE(kc + 2, b);
        SCHEDB();
        if (kc < 11) {
            #pragma unroll
            for (int ks = 0; ks < 2; ++ks)
                #pragma unroll
                for (int oi = 0; oi < 12; ++oi) {
                    acc[oi] = __builtin_amdgcn_mfma_f32_16x16x32_bf16(
                        a[ks], W[ks][oi], acc[oi], 0, 0, 0);
                    W[ks][oi] = *(const bf16x8*)(W1b +
                        ((oi * 24 + (kc + 1) * 2 + ks) << 9) + lane * 8);
                }
        } else {
            #pragma unroll
            for (int ks = 0; ks < 2; ++ks)
                #pragma unroll
                for (int oi = 0; oi < 12; ++oi)
                    acc[oi] = __builtin_amdgcn_mfma_f32_16x16x32_bf16(
                        a[ks], W[ks][oi], acc[oi], 0, 0, 0);
        }
    }

    // ---------------- bias + Q/K/VT -> own strip (X dead for this wave) ----------------
    // acc[oi][r] = QKV[n = 16wid + 4g + r][o = 16oi + c]
    #pragma unroll
    for (int oi = 0; oi < 12; ++oi) {
        float bi = b1v[16 * oi + c];
        f32x4 v = acc[oi];
        if (oi < 4) {              // Q private [n-local][d], stride 72
            #pragma unroll
            for (int r = 0; r < 4; ++r)
                S[qb + (4 * g + r) * 72 + 16 * oi + c] = f2b(v[r] + bi);
        } else if (oi < 8) {       // K [n-local][d], stride 72, @1280
            #pragma unroll
            for (int r = 0; r < 4; ++r)
                S[qb + 1280 + (4 * g + r) * 72 + 16 * (oi - 4) + c] = f2b(v[r] + bi);
        } else {                   // VT-block [d][n-local 16], stride 16, @2432
            s16x4 sv;
            sv[0] = f2b(v[0] + bi); sv[1] = f2b(v[1] + bi);
            sv[2] = f2b(v[2] + bi); sv[3] = f2b(v[3] + bi);
            *(s16x4*)&S[qb + 2432 + (16 * (oi - 8) + c) * 16 + 4 * g] = sv;
        }
    }
    __syncthreads();   // the kernel's ONLY barrier: K/VT of all waves visible

    // ---------------- S = Q K^T (q-rows = own 16 rows) ----------------
    f32x4 sc[4];
    #pragma unroll
    for (int mt = 0; mt < 4; ++mt) sc[mt] = zero4;
    #pragma unroll
    for (int ks = 0; ks < 2; ++ks) {
        bf16x8 aq = *(const bf16x8*)&S[qb + c * 72 + 32 * ks + 8 * g];
        #pragma unroll
        for (int mt = 0; mt < 4; ++mt) {   // K rows 16mt..+15 live in wave mt's strip
            bf16x8 bk = *(const bf16x8*)&S[mt * 4096 + 1280 + c * 72 + 32 * ks + 8 * g];
            sc[mt] = __builtin_amdgcn_mfma_f32_16x16x32_bf16(aq, bk, sc[mt], 0, 0, 0);
        }
    }

    // ---------------- softmax (k = 16mt + c; reduce in-lane over mt, shfl over c) ----
    float p[4][4];
    const float kS = 0.125f * 1.44269504088896f;
    #pragma unroll
    for (int r = 0; r < 4; ++r) {
        float m0 = fmaxf(fmaxf(sc[0][r], sc[1][r]), fmaxf(sc[2][r], sc[3][r]));
        m0 = fmaxf(m0, __shfl_xor(m0, 1));
        m0 = fmaxf(m0, __shfl_xor(m0, 2));
        m0 = fmaxf(m0, __shfl_xor(m0, 4));
        m0 = fmaxf(m0, __shfl_xor(m0, 8));
        float s0 = 0.f, pr[4];
        #pragma unroll
        for (int mt = 0; mt < 4; ++mt) { pr[mt] = exp2f((sc[mt][r] - m0) * kS); s0 += pr[mt]; }
        s0 += __shfl_xor(s0, 1);
        s0 += __shfl_xor(s0, 2);
        s0 += __shfl_xor(s0, 4);
        s0 += __shfl_xor(s0, 8);
        float inv = __builtin_amdgcn_rcpf(s0);
        #pragma unroll
        for (int mt = 0; mt < 4; ++mt) p[mt][r] = pr[mt] * inv;
    }

    // ---------------- P^T -> private scratch (overlays Q; Q reads done) ----------------
    #pragma unroll
    for (int mt = 0; mt < 4; ++mt) {
        s16x4 sv;
        sv[0] = f2b(p[mt][0]); sv[1] = f2b(p[mt][1]);
        sv[2] = f2b(p[mt][2]); sv[3] = f2b(p[mt][3]);
        *(s16x4*)&S[qb + (16 * mt + c) * 20 + 4 * g] = sv;
    }

    // ---------------- Y^T = V^T @ P^T ----------------
    f32x4 y4[4];
    #pragma unroll
    for (int it = 0; it < 4; ++it) y4[it] = zero4;
    #pragma unroll
    for (int ks = 0; ks < 2; ++ks) {
        bf16x8 pb;
        #pragma unroll
        for (int j = 0; j < 8; ++j)
            pb[j] = S[qb + (32 * ks + 8 * g + j) * 20 + c];
        #pragma unroll
        for (int it = 0; it < 4; ++it) {   // VT n-slice 32ks+8g.. lives in wave (2ks+(g>>1))'s strip
            bf16x8 av = *(const bf16x8*)&S[(2 * ks + (g >> 1)) * 4096 + 2432
                                           + (16 * it + c) * 16 + 8 * (g & 1)];
            y4[it] = __builtin_amdgcn_mfma_f32_16x16x32_bf16(av, pb, y4[it], 0, 0, 0);
        }
    }
    // Y repack via scratch (overlays PT; PT reads done)
    #pragma unroll
    for (int it = 0; it < 4; ++it) {
        s16x4 sv;
        sv[0] = f2b(y4[it][0]); sv[1] = f2b(y4[it][1]);
        sv[2] = f2b(y4[it][2]); sv[3] = f2b(y4[it][3]);
        *(s16x4*)&S[qb + c * 72 + 16 * it + 4 * g] = sv;
    }
    bf16x8 ay0 = *(const bf16x8*)&S[qb + c * 72 + 8 * g];
    bf16x8 ay1 = *(const bf16x8*)&S[qb + c * 72 + 32 + 8 * g];

    // ---------------- proj2 (R13 form): chunked accumulators, scalar stores ----------------
    float* orow = out + ((size_t)win * 64 + 16 * wid) * 768;
    #pragma unroll 1
    for (int ch = 0; ch < 6; ++ch) {
        f32x4 a2[8];
        #pragma unroll
        for (int i = 0; i < 8; ++i) a2[i] = zero4;
        #pragma unroll
        for (int oi = 0; oi < 8; ++oi) {
            int u = ch * 8 + oi;
            bf16x8 bw0 = *(const bf16x8*)(W2b + (2 * u) * 512 + lane * 8);
            a2[oi] = __builtin_amdgcn_mfma_f32_16x16x32_bf16(ay0, bw0, a2[oi], 0, 0, 0);
            bf16x8 bw1 = *(const bf16x8*)(W2b + (2 * u + 1) * 512 + lane * 8);
            a2[oi] = __builtin_amdgcn_mfma_f32_16x16x32_bf16(ay1, bw1, a2[oi], 0, 0, 0);
        }
        #pragma unroll
        for (int oi = 0; oi < 8; ++oi) {
            int o = 16 * (ch * 8 + oi) + c;
            float bias = b2v[o];
            #pragma unroll
            for (int r = 0; r < 4; ++r)
                orow[(size_t)(4 * g + r) * 768 + o] = a2[oi][r] + bias;
        }
    }
}

// Correctness-only fallback (ws too small): naive fp32 per-window kernel.
__global__ __launch_bounds__(256)
void tiny_att_fb(const float* __restrict__ x, const float* __restrict__ W1,
                 const float* __restrict__ b1, const float* __restrict__ W2,
                 const float* __restrict__ b2, float* __restrict__ out) {
    __shared__ float QKV[64][200];
    __shared__ float Y[64][64];
    const int win = blockIdx.x, tid = threadIdx.x;
    const float* xw = x + (size_t)win * 49152;
    for (int t = tid; t < 64 * 192; t += 256) {
        int n = t / 192, o = t % 192;
        float s = b1[o];
        for (int k = 0; k < 768; ++k) s += xw[n * 768 + k] * W1[o * 768 + k];
        QKV[n][o] = s;
    }
    __syncthreads();
    if (tid < 64) {
        int q = tid;
        float scr[64], m = -1e30f;
        for (int k = 0; k < 64; ++k) {
            float s = 0;
            for (int d = 0; d < 64; ++d) s += QKV[q][d] * QKV[k][64 + d];
            scr[k] = s * 0.125f; m = fmaxf(m, scr[k]);
        }
        float den = 0;
        for (int k = 0; k < 64; ++k) { scr[k] = __expf(scr[k] - m); den += scr[k]; }
        float inv = 1.f / den;
        for (int d = 0; d < 64; ++d) {
            float y = 0;
            for (int k = 0; k < 64; ++k) y += scr[k] * QKV[k][128 + d];
            Y[q][d] = y * inv;
        }
    }
    __syncthreads();
    for (int t = tid; t < 64 * 768; t += 256) {
        int n = t / 768, o = t % 768;
        float s = b2[o];
        for (int d = 0; d < 64; ++d) s += Y[n][d] * W2[o * 64 + d];
        out[(size_t)win * 49152 + t] = s;
    }
}

extern "C" void kernel_launch(void* const* d_in, const int* in_sizes, int n_in,
                              void* d_out, int out_size, void* d_ws, size_t ws_size,
                              hipStream_t stream) {
    const float* x  = (const float*)d_in[0];
    const float* W1 = (const float*)d_in[1];
    const float* b1 = (const float*)d_in[2];
    const float* W2 = (const float*)d_in[3];
    const float* b2 = (const float*)d_in[4];
    float* out = (float*)d_out;
    const int nwin = in_sizes[0] / (64 * 768);   // 2048 windows
    const size_t need = (size_t)(192 * 768 + 768 * 64) * sizeof(short);
    if (ws_size >= need) {
        short* w1b = (short*)d_ws;
        short* w2b = w1b + 192 * 768;
        cvt_weights<<<576, 256, 0, stream>>>(W1, W2, w1b, w2b);
        tiny_att<<<nwin, 256, 0, stream>>>(x, b1, b2, w1b, w2b, out);
    } else {
        tiny_att_fb<<<nwin, 256, 0, stream>>>(x, W1, b1, W2, b2, out);
    }
}

// Round 15
// 281.405 us; speedup vs baseline: 5.4282x; 5.4282x over previous
//
#include <hip/hip_runtime.h>
#include <hip/hip_bf16.h>

typedef __attribute__((ext_vector_type(8))) short bf16x8;
typedef __attribute__((ext_vector_type(4))) short s16x4;
typedef __attribute__((ext_vector_type(4))) float f32x4;

// LDS layout (bytes):
//  proj1 phase:   [0, 32768) X double-buffer 2 x [64 rows][64 f32], LINEAR dest,
//                 16B-slot index XOR-swizzled on the SOURCE side (both-sides rule)
//  post-proj1 (aliases X region after full pipe drain + barrier), shorts:
//                 QK [64][136] @0 (Q cols 0..63, K 64..127, pad 8)   -> 8704 shorts
//                 VT [64][72]  @8704                                  -> 4608 shorts
//                 per-wave scratch @13312 + wid*1280 (PT 64x20 / Y 16x72 overlay)
//  total 18432 shorts = 36864 B -> 4 blocks/CU
#define XBUF(b)   ((b) * 16384)
#define QKS       136
#define VT_SH     8704
#define SCR_SH    13312
#define LDS_BYTES 36864

__device__ __forceinline__ short f2b(float f) {
    __hip_bfloat16 h = __float2bfloat16(f);
    return __builtin_bit_cast(short, h);
}

// Fragment-major weight packing (R10 layout): W1 block (ot*24 + k32), W2 block (u*2+half),
// each 512 shorts lane-major; kernel loads base + lane*16B (coalesced).
__global__ void cvt_weights(const float* __restrict__ W1, const float* __restrict__ W2,
                            short* __restrict__ w1b, short* __restrict__ w2b) {
    int i = blockIdx.x * 256 + threadIdx.x;          // 576 blocks x 256 = 147456
    if (i < 192 * 768) {
        int B = i >> 9, r = i & 511;
        int lane = r >> 3, j = r & 7;
        int g = lane >> 4, c = lane & 15;
        int ot = B / 24, k32 = B - ot * 24;
        w1b[i] = f2b(W1[(16 * ot + c) * 768 + k32 * 32 + 8 * g + j]);
    }
    if (i < 768 * 64) {
        int B = i >> 9, r = i & 511;
        int lane = r >> 3, j = r & 7;
        int g = lane >> 4, c = lane & 15;
        int u = B >> 1, half = B & 1;
        w2b[i] = f2b(W2[(16 * u + c) * 64 + half * 32 + 8 * g + j]);
    }
}

__device__ __forceinline__ void gload_lds16(const float* g, unsigned char* l) {
    __builtin_amdgcn_global_load_lds(
        (const __attribute__((address_space(1))) void*)g,
        (__attribute__((address_space(3))) void*)l, 16, 0, 0);
}

#define VMWAIT(n) asm volatile("s_waitcnt vmcnt(" #n ")" ::: "memory")

#define STAGE_CHUNK(kc, b) do {                                                     \
    _Pragma("unroll")                                                               \
    for (int j = 0; j < 4; ++j) {                                                   \
        int rr = (wid * 4 + j) * 4 + (lane >> 4);                                   \
        int ss = lane & 15;                                                         \
        const float* gsrc = xg + rr * 768 + (kc) * 64 + ((ss ^ (rr & 15)) << 2);    \
        gload_lds16(gsrc, &L[XBUF(b) + (wid * 4 + j) * 1024]);                      \
    }                                                                               \
} while (0)

#define WPREF(kc, W) do {                                                           \
    _Pragma("unroll")                                                               \
    for (int ks = 0; ks < 2; ++ks)                                                  \
        _Pragma("unroll")                                                           \
        for (int oi = 0; oi < 3; ++oi)                                              \
            W[ks*3+oi] = *(const bf16x8*)(W1b +                                     \
                ((wid + 4*oi) * 24 + (kc)*2 + ks) * 512 + lane * 8);                \
} while (0)

// acc1[rt*3+oi][r] = QKV[16rt+4g+r][16(wid+4oi)+c]
#define COMPUTE(kc, b, W) do {                                                      \
    const unsigned char* Lb = &L[XBUF(b)];                                          \
    _Pragma("unroll")                                                               \
    for (int ks = 0; ks < 2; ++ks) {                                                \
        bf16x8 a[4];                                                                \
        _Pragma("unroll")                                                           \
        for (int rt = 0; rt < 4; ++rt) {                                            \
            int r = 16*rt + c;                                                      \
            int s0 = (8*ks + 2*g) ^ (r & 15);                                       \
            int s1 = (8*ks + 2*g + 1) ^ (r & 15);                                   \
            f32x4 lo = *(const f32x4*)(Lb + r*256 + s0*16);                         \
            f32x4 hi = *(const f32x4*)(Lb + r*256 + s1*16);                         \
            a[rt][0]=f2b(lo[0]); a[rt][1]=f2b(lo[1]);                               \
            a[rt][2]=f2b(lo[2]); a[rt][3]=f2b(lo[3]);                               \
            a[rt][4]=f2b(hi[0]); a[rt][5]=f2b(hi[1]);                               \
            a[rt][6]=f2b(hi[2]); a[rt][7]=f2b(hi[3]);                               \
        }                                                                           \
        _Pragma("unroll")                                                           \
        for (int oi = 0; oi < 3; ++oi)                                              \
            _Pragma("unroll")                                                       \
            for (int rt = 0; rt < 4; ++rt)                                          \
                acc1[rt*3+oi] = __builtin_amdgcn_mfma_f32_16x16x32_bf16(            \
                    a[rt], W[ks*3+oi], acc1[rt*3+oi], 0, 0, 0);                     \
    }                                                                               \
} while (0)

// steady: newer-than-stage(kc) = W(kc)6 + stage(kc+1)4 -> vmcnt(10); kc=11 -> 6
#define PIPE_ITER(kc, b, Wc, Wn) do {                                               \
    if ((kc) != 11) { VMWAIT(10); } else { VMWAIT(6); }                             \
    __builtin_amdgcn_sched_barrier(0);                                              \
    __builtin_amdgcn_s_barrier();                                                   \
    __builtin_amdgcn_sched_barrier(0);                                              \
    COMPUTE(kc, b, Wc);                                                             \
    if ((kc) + 1 < 12) WPREF((kc)+1, Wn);                                           \
    asm volatile("s_waitcnt lgkmcnt(0)" ::: "memory");                              \
    __builtin_amdgcn_sched_barrier(0);                                              \
    __builtin_amdgcn_s_barrier();                                                   \
    __builtin_amdgcn_sched_barrier(0);                                              \
    if ((kc) + 2 < 12) STAGE_CHUNK((kc)+2, b);                                      \
} while (0)

__global__ __launch_bounds__(256, 4)
void tiny_att(const float* __restrict__ x, const float* __restrict__ b1v,
              const float* __restrict__ b2v, const short* __restrict__ W1b,
              const short* __restrict__ W2b, float* __restrict__ out) {
    __shared__ __align__(16) unsigned char L[LDS_BYTES];
    short* S = (short*)L;
    const int tid  = threadIdx.x;
    const int wid  = tid >> 6;
    const int lane = tid & 63;
    const int g    = lane >> 4;
    const int c    = lane & 15;
    const int win  = blockIdx.x;
    const float* xg = x + (size_t)win * (64 * 768);
    const f32x4 zero4 = {0.f, 0.f, 0.f, 0.f};

    // ---------------- proj1: QKV[64][192] = X @ W1^T, async-pipelined ----------------
    f32x4 acc1[12];
    #pragma unroll
    for (int i = 0; i < 12; ++i) acc1[i] = zero4;

    bf16x8 Wa[6], Wb[6];
    STAGE_CHUNK(0, 0);
    STAGE_CHUNK(1, 1);
    WPREF(0, Wa);

    #pragma unroll 1
    for (int kc = 0; kc < 12; kc += 2) {
        PIPE_ITER(kc,     0, Wa, Wb);
        PIPE_ITER(kc + 1, 1, Wb, Wa);
    }
    __syncthreads();   // full pipe drain; X region dead -> QK/VT/scratch alias it

    // ---------------- bias + QKV -> LDS (aliased region) ----------------
    #pragma unroll
    for (int oi = 0; oi < 3; ++oi) {
        int ot = wid + 4 * oi;
        int o  = 16 * ot + c;
        float bias = b1v[o];
        #pragma unroll
        for (int rt = 0; rt < 4; ++rt) {
            f32x4 v = acc1[rt * 3 + oi];
            if (oi < 2) {        // Q (o<64), K (64..127): [n][o], stride QKS=136, base 0
                #pragma unroll
                for (int r = 0; r < 4; ++r)
                    S[(16 * rt + 4 * g + r) * QKS + o] = f2b(v[r] + bias);
            } else {             // VT[d][n], stride 72, base VT_SH
                int d = o - 128;
                s16x4 sv;
                sv[0] = f2b(v[0] + bias); sv[1] = f2b(v[1] + bias);
                sv[2] = f2b(v[2] + bias); sv[3] = f2b(v[3] + bias);
                *(s16x4*)&S[VT_SH + d * 72 + 16 * rt + 4 * g] = sv;
            }
        }
    }
    __syncthreads();

    // ---------------- S = Q K^T (wave: q-rows 16wid..16wid+15) ----------------
    f32x4 sc[4];
    #pragma unroll
    for (int mt = 0; mt < 4; ++mt) sc[mt] = zero4;
    #pragma unroll
    for (int ks = 0; ks < 2; ++ks) {
        bf16x8 aq = *(const bf16x8*)&S[(16 * wid + c) * QKS + 32 * ks + 8 * g];
        #pragma unroll
        for (int mt = 0; mt < 4; ++mt) {
            bf16x8 bk = *(const bf16x8*)&S[(16 * mt + c) * QKS + 64 + 32 * ks + 8 * g];
            sc[mt] = __builtin_amdgcn_mfma_f32_16x16x32_bf16(aq, bk, sc[mt], 0, 0, 0);
        }
    }

    // ---------------- softmax ----------------
    float p[4][4];
    const float kS = 0.125f * 1.44269504088896f;
    #pragma unroll
    for (int r = 0; r < 4; ++r) {
        float m0 = fmaxf(fmaxf(sc[0][r], sc[1][r]), fmaxf(sc[2][r], sc[3][r]));
        m0 = fmaxf(m0, __shfl_xor(m0, 1));
        m0 = fmaxf(m0, __shfl_xor(m0, 2));
        m0 = fmaxf(m0, __shfl_xor(m0, 4));
        m0 = fmaxf(m0, __shfl_xor(m0, 8));
        float s0 = 0.f;
        float pr[4];
        #pragma unroll
        for (int mt = 0; mt < 4; ++mt) { pr[mt] = exp2f((sc[mt][r] - m0) * kS); s0 += pr[mt]; }
        s0 += __shfl_xor(s0, 1);
        s0 += __shfl_xor(s0, 2);
        s0 += __shfl_xor(s0, 4);
        s0 += __shfl_xor(s0, 8);
        float inv = __builtin_amdgcn_rcpf(s0);
        #pragma unroll
        for (int mt = 0; mt < 4; ++mt) p[mt][r] = pr[mt] * inv;
    }

    // ---------------- P^T -> per-wave scratch ----------------
    const int ptb = SCR_SH + wid * 1280;
    #pragma unroll
    for (int mt = 0; mt < 4; ++mt) {
        s16x4 sv;
        sv[0] = f2b(p[mt][0]); sv[1] = f2b(p[mt][1]);
        sv[2] = f2b(p[mt][2]); sv[3] = f2b(p[mt][3]);
        *(s16x4*)&S[ptb + (16 * mt + c) * 20 + 4 * g] = sv;
    }

    // ---------------- Y^T = V^T @ P^T ----------------
    f32x4 y4[4];
    #pragma unroll
    for (int it = 0; it < 4; ++it) y4[it] = zero4;
    #pragma unroll
    for (int ks = 0; ks < 2; ++ks) {
        bf16x8 pb;
        #pragma unroll
        for (int j = 0; j < 8; ++j)
            pb[j] = S[ptb + (32 * ks + 8 * g + j) * 20 + c];
        #pragma unroll
        for (int it = 0; it < 4; ++it) {
            bf16x8 av = *(const bf16x8*)&S[VT_SH + (16 * it + c) * 72 + 32 * ks + 8 * g];
            y4[it] = __builtin_amdgcn_mfma_f32_16x16x32_bf16(av, pb, y4[it], 0, 0, 0);
        }
    }
    // Y repack via scratch (aliases PT; this wave's PT reads done)
    #pragma unroll
    for (int it = 0; it < 4; ++it) {
        s16x4 sv;
        sv[0] = f2b(y4[it][0]); sv[1] = f2b(y4[it][1]);
        sv[2] = f2b(y4[it][2]); sv[3] = f2b(y4[it][3]);
        *(s16x4*)&S[ptb + c * 72 + 16 * it + 4 * g] = sv;
    }
    bf16x8 ay0 = *(const bf16x8*)&S[ptb + c * 72 + 8 * g];
    bf16x8 ay1 = *(const bf16x8*)&S[ptb + c * 72 + 32 + 8 * g];

    // ---------------- proj2 (R13 form): chunked accumulators, scalar stores ----------------
    float* orow = out + ((size_t)win * 64 + 16 * wid) * 768;
    #pragma unroll 1
    for (int ch = 0; ch < 6; ++ch) {
        f32x4 a2[8];
        #pragma unroll
        for (int i = 0; i < 8; ++i) a2[i] = zero4;
        #pragma unroll
        for (int oi = 0; oi < 8; ++oi) {
            int u = ch * 8 + oi;
            bf16x8 bw0 = *(const bf16x8*)(W2b + (2 * u) * 512 + lane * 8);
            a2[oi] = __builtin_amdgcn_mfma_f32_16x16x32_bf16(ay0, bw0, a2[oi], 0, 0, 0);
            bf16x8 bw1 = *(const bf16x8*)(W2b + (2 * u + 1) * 512 + lane * 8);
            a2[oi] = __builtin_amdgcn_mfma_f32_16x16x32_bf16(ay1, bw1, a2[oi], 0, 0, 0);
        }
        #pragma unroll
        for (int oi = 0; oi < 8; ++oi) {
            int o = 16 * (ch * 8 + oi) + c;
            float bias = b2v[o];
            #pragma unroll
            for (int r = 0; r < 4; ++r)
                orow[(size_t)(4 * g + r) * 768 + o] = a2[oi][r] + bias;
        }
    }
}

// Correctness-only fallback (ws too small): naive fp32 per-window kernel.
__global__ __launch_bounds__(256)
void tiny_att_fb(const float* __restrict__ x, const float* __restrict__ W1,
                 const float* __restrict__ b1, const float* __restrict__ W2,
                 const float* __restrict__ b2, float* __restrict__ out) {
    __shared__ float QKV[64][200];
    __shared__ float Y[64][64];
    const int win = blockIdx.x, tid = threadIdx.x;
    const float* xw = x + (size_t)win * 49152;
    for (int t = tid; t < 64 * 192; t += 256) {
        int n = t / 192, o = t % 192;
        float s = b1[o];
        for (int k = 0; k < 768; ++k) s += xw[n * 768 + k] * W1[o * 768 + k];
        QKV[n][o] = s;
    }
    __syncthreads();
    if (tid < 64) {
        int q = tid;
        float scr[64], m = -1e30f;
        for (int k = 0; k < 64; ++k) {
            float s = 0;
            for (int d = 0; d < 64; ++d) s += QKV[q][d] * QKV[k][64 + d];
            scr[k] = s * 0.125f; m = fmaxf(m, scr[k]);
        }
        float den = 0;
        for (int k = 0; k < 64; ++k) { scr[k] = __expf(scr[k] - m); den += scr[k]; }
        float inv = 1.f / den;
        for (int d = 0; d < 64; ++d) {
            float y = 0;
            for (int k = 0; k < 64; ++k) y += scr[k] * QKV[k][128 + d];
            Y[q][d] = y * inv;
        }
    }
    __syncthreads();
    for (int t = tid; t < 64 * 768; t += 256) {
        int n = t / 768, o = t % 768;
        float s = b2[o];
        for (int d = 0; d < 64; ++d) s += Y[n][d] * W2[o * 64 + d];
        out[(size_t)win * 49152 + t] = s;
    }
}

extern "C" void kernel_launch(void* const* d_in, const int* in_sizes, int n_in,
                              void* d_out, int out_size, void* d_ws, size_t ws_size,
                              hipStream_t stream) {
    const float* x  = (const float*)d_in[0];
    const float* W1 = (const float*)d_in[1];
    const float* b1 = (const float*)d_in[2];
    const float* W2 = (const float*)d_in[3];
    const float* b2 = (const float*)d_in[4];
    float* out = (float*)d_out;
    const int nwin = in_sizes[0] / (64 * 768);   // 2048 windows
    const size_t need = (size_t)(192 * 768 + 768 * 64) * sizeof(short);
    if (ws_size >= need) {
        short* w1b = (short*)d_ws;
        short* w2b = w1b + 192 * 768;
        cvt_weights<<<576, 256, 0, stream>>>(W1, W2, w1b, w2b);
        tiny_att<<<nwin, 256, 0, stream>>>(x, b1, b2, w1b, w2b, out);
    } else {
        tiny_att_fb<<<nwin, 256, 0, stream>>>(x, W1, b1, W2, b2, out);
    }
}

// Round 16
// 197.247 us; speedup vs baseline: 7.7442x; 1.4267x over previous
//
#include <hip/hip_runtime.h>
#include <hip/hip_bf16.h>

typedef __attribute__((ext_vector_type(8))) short bf16x8;
typedef __attribute__((ext_vector_type(4))) short s16x4;
typedef __attribute__((ext_vector_type(4))) float f32x4;

// LDS layout (bytes):
//  proj1 phase:   [0, 32768) X double-buffer 2 x [64 rows][64 f32], LINEAR dest,
//                 16B-slot index XOR-swizzled on the SOURCE side (both-sides rule)
//  post-proj1 (aliases X region after full pipe drain + barrier), shorts:
//                 QK [64][136] @0 (Q cols 0..63, K 64..127, pad 8)   -> 8704 shorts
//                 VT [64][72]  @8704                                  -> 4608 shorts
//                 per-wave scratch @13312 + wid*1280 (PT 64x20 / Y 16x72 overlay)
//  total 18432 shorts = 36864 B -> 4 blocks/CU by LDS; VGPR ~84 (84<=128) keeps 4 resident
#define XBUF(b)   ((b) * 16384)
#define QKS       136
#define VT_SH     8704
#define SCR_SH    13312
#define LDS_BYTES 36864

__device__ __forceinline__ short f2b(float f) {
    __hip_bfloat16 h = __float2bfloat16(f);
    return __builtin_bit_cast(short, h);
}

// Fragment-major weight packing (R10 layout): W1 block (ot*24 + k32), W2 block (u*2+half),
// each 512 shorts lane-major; kernel loads base + lane*16B (coalesced).
__global__ void cvt_weights(const float* __restrict__ W1, const float* __restrict__ W2,
                            short* __restrict__ w1b, short* __restrict__ w2b) {
    int i = blockIdx.x * 256 + threadIdx.x;          // 576 blocks x 256 = 147456
    if (i < 192 * 768) {
        int B = i >> 9, r = i & 511;
        int lane = r >> 3, j = r & 7;
        int g = lane >> 4, c = lane & 15;
        int ot = B / 24, k32 = B - ot * 24;
        w1b[i] = f2b(W1[(16 * ot + c) * 768 + k32 * 32 + 8 * g + j]);
    }
    if (i < 768 * 64) {
        int B = i >> 9, r = i & 511;
        int lane = r >> 3, j = r & 7;
        int g = lane >> 4, c = lane & 15;
        int u = B >> 1, half = B & 1;
        w2b[i] = f2b(W2[(16 * u + c) * 64 + half * 32 + 8 * g + j]);
    }
}

__device__ __forceinline__ void gload_lds16(const float* g, unsigned char* l) {
    __builtin_amdgcn_global_load_lds(
        (const __attribute__((address_space(1))) void*)g,
        (__attribute__((address_space(3))) void*)l, 16, 0, 0);
}

#define VMWAIT(n) asm volatile("s_waitcnt vmcnt(" #n ")" ::: "memory")

#define STAGE_CHUNK(kc, b) do {                                                     \
    _Pragma("unroll")                                                               \
    for (int j = 0; j < 4; ++j) {                                                   \
        int rr = (wid * 4 + j) * 4 + (lane >> 4);                                   \
        int ss = lane & 15;                                                         \
        const float* gsrc = xg + rr * 768 + (kc) * 64 + ((ss ^ (rr & 15)) << 2);    \
        gload_lds16(gsrc, &L[XBUF(b) + (wid * 4 + j) * 1024]);                      \
    }                                                                               \
} while (0)

#define WPREF(kc, W) do {                                                           \
    _Pragma("unroll")                                                               \
    for (int ks = 0; ks < 2; ++ks)                                                  \
        _Pragma("unroll")                                                           \
        for (int oi = 0; oi < 3; ++oi)                                              \
            W[ks*3+oi] = *(const bf16x8*)(W1b +                                     \
                ((wid + 4*oi) * 24 + (kc)*2 + ks) * 512 + lane * 8);                \
} while (0)

// acc1[rt*3+oi][r] = QKV[16rt+4g+r][16(wid+4oi)+c]
#define COMPUTE(kc, b, W) do {                                                      \
    const unsigned char* Lb = &L[XBUF(b)];                                          \
    _Pragma("unroll")                                                               \
    for (int ks = 0; ks < 2; ++ks) {                                                \
        bf16x8 a[4];                                                                \
        _Pragma("unroll")                                                           \
        for (int rt = 0; rt < 4; ++rt) {                                            \
            int r = 16*rt + c;                                                      \
            int s0 = (8*ks + 2*g) ^ (r & 15);                                       \
            int s1 = (8*ks + 2*g + 1) ^ (r & 15);                                   \
            f32x4 lo = *(const f32x4*)(Lb + r*256 + s0*16);                         \
            f32x4 hi = *(const f32x4*)(Lb + r*256 + s1*16);                         \
            a[rt][0]=f2b(lo[0]); a[rt][1]=f2b(lo[1]);                               \
            a[rt][2]=f2b(lo[2]); a[rt][3]=f2b(lo[3]);                               \
            a[rt][4]=f2b(hi[0]); a[rt][5]=f2b(hi[1]);                               \
            a[rt][6]=f2b(hi[2]); a[rt][7]=f2b(hi[3]);                               \
        }                                                                           \
        _Pragma("unroll")                                                           \
        for (int oi = 0; oi < 3; ++oi)                                              \
            _Pragma("unroll")                                                       \
            for (int rt = 0; rt < 4; ++rt)                                          \
                acc1[rt*3+oi] = __builtin_amdgcn_mfma_f32_16x16x32_bf16(            \
                    a[rt], W[ks*3+oi], acc1[rt*3+oi], 0, 0, 0);                     \
    }                                                                               \
} while (0)

// steady: newer-than-stage(kc) = W(kc)6 + stage(kc+1)4 -> vmcnt(10); kc=11 -> 6
#define PIPE_ITER(kc, b, Wc, Wn) do {                                               \
    if ((kc) != 11) { VMWAIT(10); } else { VMWAIT(6); }                             \
    __builtin_amdgcn_sched_barrier(0);                                              \
    __builtin_amdgcn_s_barrier();                                                   \
    __builtin_amdgcn_sched_barrier(0);                                              \
    COMPUTE(kc, b, Wc);                                                             \
    if ((kc) + 1 < 12) WPREF((kc)+1, Wn);                                           \
    asm volatile("s_waitcnt lgkmcnt(0)" ::: "memory");                              \
    __builtin_amdgcn_sched_barrier(0);                                              \
    __builtin_amdgcn_s_barrier();                                                   \
    __builtin_amdgcn_sched_barrier(0);                                              \
    if ((kc) + 2 < 12) STAGE_CHUNK((kc)+2, b);                                      \
} while (0)

__global__ __launch_bounds__(256, 3)
void tiny_att(const float* __restrict__ x, const float* __restrict__ b1v,
              const float* __restrict__ b2v, const short* __restrict__ W1b,
              const short* __restrict__ W2b, float* __restrict__ out) {
    __shared__ __align__(16) unsigned char L[LDS_BYTES];
    short* S = (short*)L;
    const int tid  = threadIdx.x;
    const int wid  = tid >> 6;
    const int lane = tid & 63;
    const int g    = lane >> 4;
    const int c    = lane & 15;
    const int win  = blockIdx.x;
    const float* xg = x + (size_t)win * (64 * 768);
    const f32x4 zero4 = {0.f, 0.f, 0.f, 0.f};

    // ---------------- proj1: QKV[64][192] = X @ W1^T, async-pipelined ----------------
    f32x4 acc1[12];
    #pragma unroll
    for (int i = 0; i < 12; ++i) acc1[i] = zero4;

    bf16x8 Wa[6], Wb[6];
    STAGE_CHUNK(0, 0);
    STAGE_CHUNK(1, 1);
    WPREF(0, Wa);

    #pragma unroll 1
    for (int kc = 0; kc < 12; kc += 2) {
        PIPE_ITER(kc,     0, Wa, Wb);
        PIPE_ITER(kc + 1, 1, Wb, Wa);
    }
    __syncthreads();   // full pipe drain; X region dead -> QK/VT/scratch alias it

    // ---------------- bias + QKV -> LDS (aliased region) ----------------
    #pragma unroll
    for (int oi = 0; oi < 3; ++oi) {
        int ot = wid + 4 * oi;
        int o  = 16 * ot + c;
        float bias = b1v[o];
        #pragma unroll
        for (int rt = 0; rt < 4; ++rt) {
            f32x4 v = acc1[rt * 3 + oi];
            if (oi < 2) {        // Q (o<64), K (64..127): [n][o], stride QKS=136, base 0
                #pragma unroll
                for (int r = 0; r < 4; ++r)
                    S[(16 * rt + 4 * g + r) * QKS + o] = f2b(v[r] + bias);
            } else {             // VT[d][n], stride 72, base VT_SH
                int d = o - 128;
                s16x4 sv;
                sv[0] = f2b(v[0] + bias); sv[1] = f2b(v[1] + bias);
                sv[2] = f2b(v[2] + bias); sv[3] = f2b(v[3] + bias);
                *(s16x4*)&S[VT_SH + d * 72 + 16 * rt + 4 * g] = sv;
            }
        }
    }
    __syncthreads();

    // ---------------- S = Q K^T (wave: q-rows 16wid..16wid+15) ----------------
    f32x4 sc[4];
    #pragma unroll
    for (int mt = 0; mt < 4; ++mt) sc[mt] = zero4;
    #pragma unroll
    for (int ks = 0; ks < 2; ++ks) {
        bf16x8 aq = *(const bf16x8*)&S[(16 * wid + c) * QKS + 32 * ks + 8 * g];
        #pragma unroll
        for (int mt = 0; mt < 4; ++mt) {
            bf16x8 bk = *(const bf16x8*)&S[(16 * mt + c) * QKS + 64 + 32 * ks + 8 * g];
            sc[mt] = __builtin_amdgcn_mfma_f32_16x16x32_bf16(aq, bk, sc[mt], 0, 0, 0);
        }
    }

    // ---------------- softmax ----------------
    float p[4][4];
    const float kS = 0.125f * 1.44269504088896f;
    #pragma unroll
    for (int r = 0; r < 4; ++r) {
        float m0 = fmaxf(fmaxf(sc[0][r], sc[1][r]), fmaxf(sc[2][r], sc[3][r]));
        m0 = fmaxf(m0, __shfl_xor(m0, 1));
        m0 = fmaxf(m0, __shfl_xor(m0, 2));
        m0 = fmaxf(m0, __shfl_xor(m0, 4));
        m0 = fmaxf(m0, __shfl_xor(m0, 8));
        float s0 = 0.f;
        float pr[4];
        #pragma unroll
        for (int mt = 0; mt < 4; ++mt) { pr[mt] = exp2f((sc[mt][r] - m0) * kS); s0 += pr[mt]; }
        s0 += __shfl_xor(s0, 1);
        s0 += __shfl_xor(s0, 2);
        s0 += __shfl_xor(s0, 4);
        s0 += __shfl_xor(s0, 8);
        float inv = __builtin_amdgcn_rcpf(s0);
        #pragma unroll
        for (int mt = 0; mt < 4; ++mt) p[mt][r] = pr[mt] * inv;
    }

    // ---------------- P^T -> per-wave scratch ----------------
    const int ptb = SCR_SH + wid * 1280;
    #pragma unroll
    for (int mt = 0; mt < 4; ++mt) {
        s16x4 sv;
        sv[0] = f2b(p[mt][0]); sv[1] = f2b(p[mt][1]);
        sv[2] = f2b(p[mt][2]); sv[3] = f2b(p[mt][3]);
        *(s16x4*)&S[ptb + (16 * mt + c) * 20 + 4 * g] = sv;
    }

    // ---------------- Y^T = V^T @ P^T ----------------
    f32x4 y4[4];
    #pragma unroll
    for (int it = 0; it < 4; ++it) y4[it] = zero4;
    #pragma unroll
    for (int ks = 0; ks < 2; ++ks) {
        bf16x8 pb;
        #pragma unroll
        for (int j = 0; j < 8; ++j)
            pb[j] = S[ptb + (32 * ks + 8 * g + j) * 20 + c];
        #pragma unroll
        for (int it = 0; it < 4; ++it) {
            bf16x8 av = *(const bf16x8*)&S[VT_SH + (16 * it + c) * 72 + 32 * ks + 8 * g];
            y4[it] = __builtin_amdgcn_mfma_f32_16x16x32_bf16(av, pb, y4[it], 0, 0, 0);
        }
    }
    // Y repack via scratch (aliases PT; this wave's PT reads done)
    #pragma unroll
    for (int it = 0; it < 4; ++it) {
        s16x4 sv;
        sv[0] = f2b(y4[it][0]); sv[1] = f2b(y4[it][1]);
        sv[2] = f2b(y4[it][2]); sv[3] = f2b(y4[it][3]);
        *(s16x4*)&S[ptb + c * 72 + 16 * it + 4 * g] = sv;
    }
    bf16x8 ay0 = *(const bf16x8*)&S[ptb + c * 72 + 8 * g];
    bf16x8 ay1 = *(const bf16x8*)&S[ptb + c * 72 + 32 + 8 * g];

    // ---------------- proj2 (R13 form): chunked accumulators, scalar stores ----------------
    float* orow = out + ((size_t)win * 64 + 16 * wid) * 768;
    #pragma unroll 1
    for (int ch = 0; ch < 6; ++ch) {
        f32x4 a2[8];
        #pragma unroll
        for (int i = 0; i < 8; ++i) a2[i] = zero4;
        #pragma unroll
        for (int oi = 0; oi < 8; ++oi) {
            int u = ch * 8 + oi;
            bf16x8 bw0 = *(const bf16x8*)(W2b + (2 * u) * 512 + lane * 8);
            a2[oi] = __builtin_amdgcn_mfma_f32_16x16x32_bf16(ay0, bw0, a2[oi], 0, 0, 0);
            bf16x8 bw1 = *(const bf16x8*)(W2b + (2 * u + 1) * 512 + lane * 8);
            a2[oi] = __builtin_amdgcn_mfma_f32_16x16x32_bf16(ay1, bw1, a2[oi], 0, 0, 0);
        }
        #pragma unroll
        for (int oi = 0; oi < 8; ++oi) {
            int o = 16 * (ch * 8 + oi) + c;
            float bias = b2v[o];
            #pragma unroll
            for (int r = 0; r < 4; ++r)
                orow[(size_t)(4 * g + r) * 768 + o] = a2[oi][r] + bias;
        }
    }
}

// Correctness-only fallback (ws too small): naive fp32 per-window kernel.
__global__ __launch_bounds__(256)
void tiny_att_fb(const float* __restrict__ x, const float* __restrict__ W1,
                 const float* __restrict__ b1, const float* __restrict__ W2,
                 const float* __restrict__ b2, float* __restrict__ out) {
    __shared__ float QKV[64][200];
    __shared__ float Y[64][64];
    const int win = blockIdx.x, tid = threadIdx.x;
    const float* xw = x + (size_t)win * 49152;
    for (int t = tid; t < 64 * 192; t += 256) {
        int n = t / 192, o = t % 192;
        float s = b1[o];
        for (int k = 0; k < 768; ++k) s += xw[n * 768 + k] * W1[o * 768 + k];
        QKV[n][o] = s;
    }
    __syncthreads();
    if (tid < 64) {
        int q = tid;
        float scr[64], m = -1e30f;
        for (int k = 0; k < 64; ++k) {
            float s = 0;
            for (int d = 0; d < 64; ++d) s += QKV[q][d] * QKV[k][64 + d];
            scr[k] = s * 0.125f; m = fmaxf(m, scr[k]);
        }
        float den = 0;
        for (int k = 0; k < 64; ++k) { scr[k] = __expf(scr[k] - m); den += scr[k]; }
        float inv = 1.f / den;
        for (int d = 0; d < 64; ++d) {
            float y = 0;
            for (int k = 0; k < 64; ++k) y += scr[k] * QKV[k][128 + d];
            Y[q][d] = y * inv;
        }
    }
    __syncthreads();
    for (int t = tid; t < 64 * 768; t += 256) {
        int n = t / 768, o = t % 768;
        float s = b2[o];
        for (int d = 0; d < 64; ++d) s += Y[n][d] * W2[o * 64 + d];
        out[(size_t)win * 49152 + t] = s;
    }
}

extern "C" void kernel_launch(void* const* d_in, const int* in_sizes, int n_in,
                              void* d_out, int out_size, void* d_ws, size_t ws_size,
                              hipStream_t stream) {
    const float* x  = (const float*)d_in[0];
    const float* W1 = (const float*)d_in[1];
    const float* b1 = (const float*)d_in[2];
    const float* W2 = (const float*)d_in[3];
    const float* b2 = (const float*)d_in[4];
    float* out = (float*)d_out;
    const int nwin = in_sizes[0] / (64 * 768);   // 2048 windows
    const size_t need = (size_t)(192 * 768 + 768 * 64) * sizeof(short);
    if (ws_size >= need) {
        short* w1b = (short*)d_ws;
        short* w2b = w1b + 192 * 768;
        cvt_weights<<<576, 256, 0, stream>>>(W1, W2, w1b, w2b);
        tiny_att<<<nwin, 256, 0, stream>>>(x, b1, b2, w1b, w2b, out);
    } else {
        tiny_att_fb<<<nwin, 256, 0, stream>>>(x, W1, b1, W2, b2, out);
    }
}